// Round 7
// baseline (1089.808 us; speedup 1.0000x reference)
//
#include <hip/hip_runtime.h>

#define ANG 9
#define HH 96
#define BB 2
#define PLANE_F (81*HH*HH)  // 746496 per channel (81 views x 96x96)
#define PLANE_A (HH*HH)     // 9216
#define NBLK_FEAT 1458      // BB*81*9 blocks (each: 256 threads, 4-row strips)
#define INV_NBIG  (1.0f / 1492992.0f)
#define INV_NSMALL (1.0f / 18432.0f)

// ===== weight pre-shuffle for BuildCost: WT[((g*7+c)*81 + u*9+v)*16 + o] =====
__global__ __launch_bounds__(256) void k_wprep(const float* __restrict__ w, float* __restrict__ wt) {
  int k = blockIdx.x * 256 + threadIdx.x;
  if (k >= 144 * 567) return;
  int o = k & 15; int rest = k >> 4;
  int r81 = rest % 81; int gc = rest / 81;
  int c = gc % 7, g = gc / 7;
  wt[k] = w[((g * 16 + o) * 7 + c) * 81 + r81];
}

// ===== 7-channel BN prologue from feature partials: fpart[k*14 + a], k<1458 =====
__device__ __forceinline__ void feat_bn_prologue(const float* __restrict__ fpart,
    const float* __restrict__ g, const float* __restrict__ bb,
    float (&s_sc)[7], float (&s_sh)[7], float (&redp)[4][14], int tid) {
  float ps[14];
  #pragma unroll
  for (int a = 0; a < 14; a++) ps[a] = 0.f;
  for (int k = tid; k < NBLK_FEAT; k += 256) {
    const float* fp = fpart + k * 14;
    #pragma unroll
    for (int a = 0; a < 14; a++) ps[a] += fp[a];
  }
  #pragma unroll
  for (int off = 32; off > 0; off >>= 1)
    #pragma unroll
    for (int a = 0; a < 14; a++) ps[a] += __shfl_down(ps[a], off);
  int wave = tid >> 6, lane = tid & 63;
  if (lane == 0) {
    #pragma unroll
    for (int a = 0; a < 14; a++) redp[wave][a] = ps[a];
  }
  __syncthreads();
  if (tid < 7) {
    float S = redp[0][tid] + redp[1][tid] + redp[2][tid] + redp[3][tid];
    float Q = redp[0][tid + 7] + redp[1][tid + 7] + redp[2][tid + 7] + redp[3][tid + 7];
    float mean = S * INV_NBIG;
    float var = fmaxf(Q * INV_NBIG - mean * mean, 0.f);
    float scale = g[tid] / sqrtf(var + 1e-5f);
    s_sc[tid] = scale; s_sh[tid] = bb[tid] - mean * scale;
  }
  __syncthreads();
}

// ===== feature conv0: 1->7 from raw x, branchless clamped window, fused stats =====
__global__ __launch_bounds__(256) void k_featconv0(const float* __restrict__ x,
    const float* __restrict__ w, float* __restrict__ out, float* __restrict__ fpart) {
  int blk = blockIdx.x, tid = threadIdx.x;
  int view = blk / 9, q = blk % 9;
  int b = view / 81, uv = view % 81;
  int u = uv / 9, v = uv % 9;
  int widx = q * 256 + tid;
  int j = widx % HH, i0 = (widx / HH) * 4;
  const float* bx = x + (size_t)b * PLANE_F + (u * HH) * 864 + v * HH;
  int off[6][3]; float m[6][3];
  #pragma unroll
  for (int r6 = 0; r6 < 6; r6++) {
    int ii = i0 + r6 - 1;
    float mi = ((unsigned)ii < 96u) ? 1.f : 0.f;
    int iic = min(max(ii, 0), 95);
    #pragma unroll
    for (int dx = 0; dx < 3; dx++) {
      int jj = j + dx - 1;
      float mj = ((unsigned)jj < 96u) ? 1.f : 0.f;
      int jjc = min(max(jj, 0), 95);
      off[r6][dx] = iic * 864 + jjc;
      m[r6][dx] = mi * mj;
    }
  }
  float win[6][3];
  #pragma unroll
  for (int r6 = 0; r6 < 6; r6++)
    #pragma unroll
    for (int dx = 0; dx < 3; dx++)
      win[r6][dx] = bx[off[r6][dx]] * m[r6][dx];
  float acc[4][7];
  #pragma unroll
  for (int px = 0; px < 4; px++)
    #pragma unroll
    for (int o = 0; o < 7; o++) acc[px][o] = 0.f;
  #pragma unroll
  for (int o = 0; o < 7; o++) {
    const float* wc = w + o * 9;
    #pragma unroll
    for (int ky = 0; ky < 3; ky++)
      #pragma unroll
      for (int kx = 0; kx < 3; kx++) {
        float wv = wc[ky * 3 + kx];
        #pragma unroll
        for (int px = 0; px < 4; px++)
          acc[px][o] = fmaf(win[px + ky][kx], wv, acc[px][o]);
      }
  }
  #pragma unroll
  for (int o = 0; o < 7; o++) {
    float* op = out + ((size_t)(b * 7 + o)) * PLANE_F + uv * PLANE_A + i0 * HH + j;
    #pragma unroll
    for (int px = 0; px < 4; px++) op[px * HH] = acc[px][o];
  }
  float sv[7], qv[7];
  #pragma unroll
  for (int o = 0; o < 7; o++) {
    sv[o] = acc[0][o] + acc[1][o] + acc[2][o] + acc[3][o];
    qv[o] = acc[0][o]*acc[0][o] + acc[1][o]*acc[1][o] + acc[2][o]*acc[2][o] + acc[3][o]*acc[3][o];
  }
  #pragma unroll
  for (int off2 = 32; off2 > 0; off2 >>= 1)
    #pragma unroll
    for (int o = 0; o < 7; o++) { sv[o] += __shfl_down(sv[o], off2); qv[o] += __shfl_down(qv[o], off2); }
  __shared__ float red[4][14];
  int wave = tid >> 6, lane = tid & 63;
  if (lane == 0) {
    #pragma unroll
    for (int o = 0; o < 7; o++) { red[wave][o] = sv[o]; red[wave][7 + o] = qv[o]; }
  }
  __syncthreads();
  if (tid < 14)
    fpart[blk * 14 + tid] = red[0][tid] + red[1][tid] + red[2][tid] + red[3][tid];
}

// ===== feature conv: 7->7, fused BN prologue + BN+ReLU + stats =====
__global__ __launch_bounds__(256) void k_featconv4(const float* __restrict__ in,
    const float* __restrict__ fpart_in, const float* __restrict__ g, const float* __restrict__ bb,
    const float* __restrict__ w, float* __restrict__ out, float* __restrict__ fpart_out) {
  __shared__ float s_sc[7], s_sh[7];
  __shared__ float redp[4][14];
  int blk = blockIdx.x, tid = threadIdx.x;
  feat_bn_prologue(fpart_in, g, bb, s_sc, s_sh, redp, tid);
  int view = blk / 9, q = blk % 9;
  int b = view / 81, uv = view % 81;
  int widx = q * 256 + tid;
  int j = widx % HH, i0 = (widx / HH) * 4;
  int off[6][3]; float m[6][3];
  #pragma unroll
  for (int r6 = 0; r6 < 6; r6++) {
    int ii = i0 + r6 - 1;
    float mi = ((unsigned)ii < 96u) ? 1.f : 0.f;
    int iic = min(max(ii, 0), 95);
    #pragma unroll
    for (int dx = 0; dx < 3; dx++) {
      int jj = j + dx - 1;
      float mj = ((unsigned)jj < 96u) ? 1.f : 0.f;
      int jjc = min(max(jj, 0), 95);
      off[r6][dx] = iic * HH + jjc;
      m[r6][dx] = mi * mj;
    }
  }
  float acc[4][7];
  #pragma unroll
  for (int px = 0; px < 4; px++)
    #pragma unroll
    for (int o = 0; o < 7; o++) acc[px][o] = 0.f;
  #pragma unroll 1
  for (int c = 0; c < 7; c++) {
    const float* ip = in + ((size_t)(b * 7 + c)) * PLANE_F + uv * PLANE_A;
    float s = s_sc[c], h2 = s_sh[c];
    float win[6][3];
    #pragma unroll
    for (int r6 = 0; r6 < 6; r6++)
      #pragma unroll
      for (int dx = 0; dx < 3; dx++) {
        float vv = ip[off[r6][dx]];
        win[r6][dx] = fmaxf(fmaf(vv, s, h2), 0.f) * m[r6][dx];
      }
    #pragma unroll
    for (int o = 0; o < 7; o++) {
      const float* wc = w + (o * 7 + c) * 9;
      #pragma unroll
      for (int ky = 0; ky < 3; ky++)
        #pragma unroll
        for (int kx = 0; kx < 3; kx++) {
          float wv = wc[ky * 3 + kx];
          #pragma unroll
          for (int px = 0; px < 4; px++)
            acc[px][o] = fmaf(win[px + ky][kx], wv, acc[px][o]);
        }
    }
  }
  #pragma unroll
  for (int o = 0; o < 7; o++) {
    float* op = out + ((size_t)(b * 7 + o)) * PLANE_F + uv * PLANE_A + i0 * HH + j;
    #pragma unroll
    for (int px = 0; px < 4; px++) op[px * HH] = acc[px][o];
  }
  float sv[7], qv[7];
  #pragma unroll
  for (int o = 0; o < 7; o++) {
    sv[o] = acc[0][o] + acc[1][o] + acc[2][o] + acc[3][o];
    qv[o] = acc[0][o]*acc[0][o] + acc[1][o]*acc[1][o] + acc[2][o]*acc[2][o] + acc[3][o]*acc[3][o];
  }
  #pragma unroll
  for (int off2 = 32; off2 > 0; off2 >>= 1)
    #pragma unroll
    for (int o = 0; o < 7; o++) { sv[o] += __shfl_down(sv[o], off2); qv[o] += __shfl_down(qv[o], off2); }
  __shared__ float red[4][14];
  int wave = tid >> 6, lane = tid & 63;
  if (lane == 0) {
    #pragma unroll
    for (int o = 0; o < 7; o++) { red[wave][o] = sv[o]; red[wave][7 + o] = qv[o]; }
  }
  __syncthreads();
  if (tid < 14)
    fpart_out[blk * 14 + tid] = red[0][tid] + red[1][tid] + red[2][tid] + red[3][tid];
}

// ===== BuildCost: BN prologue, hoisted offsets/masks, distance-2 prefetch =====
// grid (18, 36, 2): x = gg (g*2+half), y = pos block, z = b
__global__ __launch_bounds__(256) void k_buildcost(const float* __restrict__ F,
    const float* __restrict__ fpart, const float* __restrict__ g7, const float* __restrict__ b7,
    const float* __restrict__ wt, float* __restrict__ cv) {
  __shared__ float s_sc[7], s_sh[7];
  __shared__ float redp[4][14];
  int tid = threadIdx.x;
  feat_bn_prologue(fpart, g7, b7, s_sc, s_sh, redp, tid);
  int gg = blockIdx.x, b = blockIdx.z;
  int g = gg >> 1, half = gg & 1;
  int d = g - 4;
  bool flip = d > 0;
  int p = blockIdx.y * 256 + tid;
  int i = p / HH, j = p % HH;
  int ubase[9]; float mi[9]; int voff[9]; float mj[9];
  #pragma unroll
  for (int u = 0; u < 9; u++) {
    int ii = i + d * (4 - u);
    mi[u] = ((unsigned)ii < 96u) ? 1.f : 0.f;
    ubase[u] = u * 9 * PLANE_A + min(max(ii, 0), 95) * HH;
  }
  #pragma unroll
  for (int v = 0; v < 9; v++) {
    int jj = j + d * (4 - v);
    mj[v] = ((unsigned)jj < 96u) ? 1.f : 0.f;
    voff[v] = v * PLANE_A + min(max(jj, 0), 95);
  }
  float acc[8];
  #pragma unroll
  for (int o = 0; o < 8; o++) acc[o] = 0.f;
  const float* Fb = F + ((size_t)b * 7) * PLANE_F;
  auto LD = [&](int cu, float* dst) {
    int c = cu / 9, u = cu - c * 9;
    const float* base = Fb + (size_t)c * PLANE_F + ubase[u];
    #pragma unroll
    for (int v = 0; v < 9; v++) dst[v] = base[voff[v]];
  };
  float buf[2][9];
  LD(0, buf[0]);
  LD(1, buf[1]);
  #pragma unroll 1
  for (int cu = 0; cu < 63; cu++) {
    int c = cu / 9, u = cu - c * 9;
    int pb = cu & 1;
    float cr[9];
    #pragma unroll
    for (int v = 0; v < 9; v++) cr[v] = buf[pb][v];
    int nf = cu + 2;
    if (nf < 63) LD(nf, buf[pb]);
    float s = s_sc[c], h2 = s_sh[c];
    float mrow = mi[u];
    int uw = flip ? 8 - u : u;
    const float* wb = wt + ((size_t)((g * 7 + c) * 81 + uw * 9)) * 16 + half * 8;
    #pragma unroll
    for (int v = 0; v < 9; v++) {
      float a = fmaxf(fmaf(cr[v], s, h2), 0.f) * (mrow * mj[v]);
      int vw = flip ? 8 - v : v;
      const float* wp = wb + vw * 16;               // uniform -> s_load
      #pragma unroll
      for (int o = 0; o < 8; o++) acc[o] = fmaf(wp[o], a, acc[o]);
    }
  }
  size_t cvb = ((size_t)(b * 144 + g * 16 + half * 8)) * PLANE_A + p;
  #pragma unroll
  for (int o = 0; o < 8; o++) cv[cvb + o * PLANE_A] = acc[o];
}

// ===== depthwise 3x3 pad=1: fused BN prologue (from pw partials) + stats out =====
// stats out layout: dps[k*C + c], k = b*36+chunk (72 total)
template<bool AFF>
__global__ __launch_bounds__(256) void k_dwconv(const float* __restrict__ in,
    const float* __restrict__ pps, const float* __restrict__ ppq,
    const float* __restrict__ g, const float* __restrict__ bbias,
    const float* __restrict__ w, float* __restrict__ out,
    float* __restrict__ dps, float* __restrict__ dpq, int C) {
  int blk = blockIdx.x, tid = threadIdx.x;
  int t = blk * 256 + tid;
  int j = t % HH; int r = t / HH; int i = r % HH; r /= HH; int c = r % C; int b = r / C;
  __shared__ float red[4][2];
  __shared__ float scsh[2];
  float s = 1.f, h2 = 0.f;
  if (AFF) {
    float s_in = 0.f, q_in = 0.f;
    if (tid < 72) { s_in = pps[tid * 180 + c]; q_in = ppq[tid * 180 + c]; }
    #pragma unroll
    for (int off = 32; off > 0; off >>= 1) { s_in += __shfl_down(s_in, off); q_in += __shfl_down(q_in, off); }
    int wave = tid >> 6, lane = tid & 63;
    if (lane == 0) { red[wave][0] = s_in; red[wave][1] = q_in; }
    __syncthreads();
    if (tid == 0) {
      float S = red[0][0] + red[1][0] + red[2][0] + red[3][0];
      float Q = red[0][1] + red[1][1] + red[2][1] + red[3][1];
      float mean = S * INV_NSMALL;
      float var = fmaxf(Q * INV_NSMALL - mean * mean, 0.f);
      float scale = g[c] / sqrtf(var + 1e-5f);
      scsh[0] = scale; scsh[1] = bbias[c] - mean * scale;
    }
    __syncthreads();
    s = scsh[0]; h2 = scsh[1];
  }
  const float* ip = in + ((size_t)(b * C + c)) * PLANE_A;
  float acc = 0.f;
  #pragma unroll
  for (int ky = 0; ky < 3; ky++) {
    int ii = i + ky - 1;
    if ((unsigned)ii >= (unsigned)HH) continue;
    #pragma unroll
    for (int kx = 0; kx < 3; kx++) {
      int jj = j + kx - 1;
      if ((unsigned)jj >= (unsigned)HH) continue;
      float v = ip[ii * HH + jj];
      if (AFF) v = fmaxf(fmaf(v, s, h2), 0.f);
      acc = fmaf(w[c * 9 + ky * 3 + kx], v, acc);
    }
  }
  out[t] = acc;
  float sv = acc, qv = acc * acc;
  #pragma unroll
  for (int off = 32; off > 0; off >>= 1) { sv += __shfl_down(sv, off); qv += __shfl_down(qv, off); }
  int wave = tid >> 6, lane = tid & 63;
  __syncthreads();
  if (lane == 0) { red[wave][0] = sv; red[wave][1] = qv; }
  __syncthreads();
  if (tid == 0) {
    float S = red[0][0] + red[1][0] + red[2][0] + red[3][0];
    float Q = red[0][1] + red[1][1] + red[2][1] + red[3][1];
    int chunk = blk % 36; int rr = blk / 36; int c2 = rr % C; int b2 = rr / C;
    dps[(b2 * 36 + chunk) * C + c2] = S;
    dpq[(b2 * 36 + chunk) * C + c2] = Q;
  }
}

// ===== pointwise conv: BN prologue (from dw partials, K ch) + stats out =====
// grid (15, 72): x = output group (12 outputs), y = position block
template<int K>
__global__ __launch_bounds__(256) void k_pwconv(const float* __restrict__ in,
    const float* __restrict__ dps, const float* __restrict__ dpq,
    const float* __restrict__ g, const float* __restrict__ bbias,
    const float* __restrict__ w, float* __restrict__ out,
    float* __restrict__ pps, float* __restrict__ ppq) {
  __shared__ float2 scsh[K];
  int tid = threadIdx.x;
  if (tid < K) {
    float S = 0.f, Q = 0.f;
    for (int k = 0; k < 72; k++) { S += dps[k * K + tid]; Q += dpq[k * K + tid]; }
    float mean = S * INV_NSMALL;
    float var = fmaxf(Q * INV_NSMALL - mean * mean, 0.f);
    float scale = g[tid] / sqrtf(var + 1e-5f);
    scsh[tid] = make_float2(scale, bbias[tid] - mean * scale);
  }
  __syncthreads();
  int posblk = blockIdx.y;
  int p = posblk * 256 + tid;
  int b = p / PLANE_A, pp = p - b * PLANE_A;
  int obase = blockIdx.x * 12;
  float acc[12];
  #pragma unroll
  for (int o = 0; o < 12; o++) acc[o] = 0.f;
  const float* ib = in + (size_t)b * K * PLANE_A + pp;
  float xn[4];
  #pragma unroll
  for (int q2 = 0; q2 < 4; q2++) xn[q2] = ib[(size_t)q2 * PLANE_A];
  #pragma unroll 1
  for (int c0 = 0; c0 < K; c0 += 4) {
    float xv[4];
    #pragma unroll
    for (int q2 = 0; q2 < 4; q2++) xv[q2] = xn[q2];
    if (c0 + 4 < K) {
      #pragma unroll
      for (int q2 = 0; q2 < 4; q2++) xn[q2] = ib[(size_t)(c0 + 4 + q2) * PLANE_A];
    }
    #pragma unroll
    for (int q2 = 0; q2 < 4; q2++) {
      int c = c0 + q2;
      float2 ss = scsh[c];
      float v = fmaxf(fmaf(xv[q2], ss.x, ss.y), 0.f);
      const float* wc = w + c;
      #pragma unroll
      for (int o = 0; o < 12; o++)
        acc[o] = fmaf(wc[(size_t)(obase + o) * K], v, acc[o]);
    }
  }
  #pragma unroll
  for (int o = 0; o < 12; o++)
    out[((size_t)(b * 180 + obase + o)) * PLANE_A + pp] = acc[o];
  __shared__ float rs[4][12], rq[4][12];
  int wave = tid >> 6, lane = tid & 63;
  #pragma unroll
  for (int o = 0; o < 12; o++) {
    float s = acc[o], q = acc[o] * acc[o];
    #pragma unroll
    for (int off = 32; off > 0; off >>= 1) { s += __shfl_down(s, off); q += __shfl_down(q, off); }
    if (lane == 0) { rs[wave][o] = s; rq[wave][o] = q; }
  }
  __syncthreads();
  if (tid < 12)
    pps[posblk * 180 + obase + tid] = rs[0][tid] + rs[1][tid] + rs[2][tid] + rs[3][tid];
  else if (tid < 24) {
    int o = tid - 12;
    ppq[posblk * 180 + obase + o] = rq[0][o] + rq[1][o] + rq[2][o] + rq[3][o];
  }
}

// ===== final: BN prologue + 1x1 conv 180->9 + softmax + expectation =====
__global__ __launch_bounds__(256) void k_final(const float* __restrict__ in,
    const float* __restrict__ dps, const float* __restrict__ dpq,
    const float* __restrict__ g, const float* __restrict__ bbias,
    const float* __restrict__ w, float* __restrict__ out) {
  __shared__ float2 scsh[180];
  int tid = threadIdx.x;
  if (tid < 180) {
    float S = 0.f, Q = 0.f;
    for (int k = 0; k < 72; k++) { S += dps[k * 180 + tid]; Q += dpq[k * 180 + tid]; }
    float mean = S * INV_NSMALL;
    float var = fmaxf(Q * INV_NSMALL - mean * mean, 0.f);
    float scale = g[tid] / sqrtf(var + 1e-5f);
    scsh[tid] = make_float2(scale, bbias[tid] - mean * scale);
  }
  __syncthreads();
  int t = blockIdx.x * 256 + tid;
  int b = t / PLANE_A, p = t - b * PLANE_A;
  const float* ib = in + (size_t)b * 180 * PLANE_A + p;
  float acc[9];
  #pragma unroll
  for (int o = 0; o < 9; o++) acc[o] = 0.f;
  float xn[4];
  #pragma unroll
  for (int q2 = 0; q2 < 4; q2++) xn[q2] = ib[(size_t)q2 * PLANE_A];
  #pragma unroll 1
  for (int c0 = 0; c0 < 180; c0 += 4) {
    float xv[4];
    #pragma unroll
    for (int q2 = 0; q2 < 4; q2++) xv[q2] = xn[q2];
    if (c0 + 4 < 180) {
      #pragma unroll
      for (int q2 = 0; q2 < 4; q2++) xn[q2] = ib[(size_t)(c0 + 4 + q2) * PLANE_A];
    }
    #pragma unroll
    for (int q2 = 0; q2 < 4; q2++) {
      int c = c0 + q2;
      float2 ss = scsh[c];
      float v = fmaxf(fmaf(xv[q2], ss.x, ss.y), 0.f);
      #pragma unroll
      for (int o = 0; o < 9; o++) acc[o] = fmaf(w[o * 180 + c], v, acc[o]);
    }
  }
  float m = acc[0];
  #pragma unroll
  for (int o = 1; o < 9; o++) m = fmaxf(m, acc[o]);
  float se = 0.f, num = 0.f;
  #pragma unroll
  for (int o = 0; o < 9; o++) {
    float e = expf(acc[o] - m);
    se += e;
    num += (float)(o - 4) * e;
  }
  out[t] = num / se;
}

extern "C" void kernel_launch(void* const* d_in, const int* in_sizes, int n_in,
                              void* d_out, int out_size, void* d_ws, size_t ws_size,
                              hipStream_t stream) {
  const float* x    = (const float*)d_in[0];
  const float* fw0  = (const float*)d_in[1];
  const float* fg0  = (const float*)d_in[2];
  const float* fb0  = (const float*)d_in[3];
  const float* fw   = (const float*)d_in[4];
  const float* fg   = (const float*)d_in[5];
  const float* fb   = (const float*)d_in[6];
  const float* bcw  = (const float*)d_in[7];
  const float* a0dw = (const float*)d_in[8];
  const float* a0dg = (const float*)d_in[9];
  const float* a0db = (const float*)d_in[10];
  const float* a0pw = (const float*)d_in[11];
  const float* a0pg = (const float*)d_in[12];
  const float* a0pb = (const float*)d_in[13];
  const float* amdw = (const float*)d_in[14];
  const float* amdg = (const float*)d_in[15];
  const float* amdb = (const float*)d_in[16];
  const float* ampw = (const float*)d_in[17];
  const float* ampg = (const float*)d_in[18];
  const float* ampb = (const float*)d_in[19];
  const float* ldw  = (const float*)d_in[20];
  const float* ldg  = (const float*)d_in[21];
  const float* ldb  = (const float*)d_in[22];
  const float* lpw  = (const float*)d_in[23];
  float* outp = (float*)d_out;

  float* FA   = (float*)d_ws;
  float* FB   = FA + (size_t)BB * 7 * PLANE_F;
  float* CV   = FB + (size_t)BB * 7 * PLANE_F;
  float* GA   = CV + (size_t)BB * 144 * PLANE_A;
  float* GB   = GA + (size_t)BB * 180 * PLANE_A;
  float* FPA  = GB + (size_t)BB * 180 * PLANE_A;    // 1458*14
  float* FPB  = FPA + NBLK_FEAT * 14;
  float* DPS  = FPB + NBLK_FEAT * 14;               // 72*180 (dw stats)
  float* DPQ  = DPS + 72 * 180;
  float* PPS  = DPQ + 72 * 180;                     // 72*180 (pw stats)
  float* PPQ  = PPS + 72 * 180;
  float* WT   = PPQ + 72 * 180;                     // 144*567

  // weight pre-shuffle for BuildCost
  k_wprep<<<(144 * 567 + 255) / 256, 256, 0, stream>>>(bcw, WT);

  // feature extraction; BN-final fused into each consumer's prologue
  k_featconv0<<<NBLK_FEAT, 256, 0, stream>>>(x, fw0, FA, FPA);

  float* cur = FA; float* nxt = FB;
  float* fcur = FPA; float* fnxt = FPB;
  for (int i = 0; i < 6; i++) {
    const float* gi = (i == 0) ? fg0 : fg + (i - 1) * 7;
    const float* bi = (i == 0) ? fb0 : fb + (i - 1) * 7;
    k_featconv4<<<NBLK_FEAT, 256, 0, stream>>>(cur, fcur, gi, bi, fw + i * 441, nxt, fnxt);
    float* tmp = cur; cur = nxt; nxt = tmp;
    tmp = fcur; fcur = fnxt; fnxt = tmp;
  }

  // BuildCost (reads fc4_5 stats from fcur with fg[5]/fb[5])
  k_buildcost<<<dim3(18, 36, 2), 256, 0, stream>>>(cur, fcur, fg + 35, fb + 35, WT, CV);

  // aggregation: BN prologues fused, no separate stats kernels
  k_dwconv<false><<<BB * 144 * 36, 256, 0, stream>>>(CV, nullptr, nullptr, nullptr, nullptr,
                                                     a0dw, GA, DPS, DPQ, 144);
  k_pwconv<144><<<dim3(15, 72), 256, 0, stream>>>(GA, DPS, DPQ, a0dg, a0db, a0pw, GB, PPS, PPQ);

  for (int m = 0; m < 4; m++) {
    const float* pg = (m == 0) ? a0pg : ampg + (m - 1) * 180;
    const float* pb = (m == 0) ? a0pb : ampb + (m - 1) * 180;
    k_dwconv<true><<<BB * 180 * 36, 256, 0, stream>>>(GB, PPS, PPQ, pg, pb,
                                                      amdw + m * 1620, GA, DPS, DPQ, 180);
    k_pwconv<180><<<dim3(15, 72), 256, 0, stream>>>(GA, DPS, DPQ, amdg + m * 180, amdb + m * 180,
                                                    ampw + m * 32400, GB, PPS, PPQ);
  }

  k_dwconv<true><<<BB * 180 * 36, 256, 0, stream>>>(GB, PPS, PPQ, ampg + 540, ampb + 540,
                                                    ldw, GA, DPS, DPQ, 180);

  k_final<<<72, 256, 0, stream>>>(GA, DPS, DPQ, ldg, ldb, lpw, outp);
}

// Round 8
// 961.474 us; speedup vs baseline: 1.1335x; 1.1335x over previous
//
#include <hip/hip_runtime.h>

#define ANG 9
#define HH 96
#define BB 2
#define PLANE_F (81*HH*HH)  // 746496 per channel (81 views x 96x96)
#define PLANE_A (HH*HH)     // 9216
#define NBLK_FEAT 1458      // BB*81*9 blocks (each: 256 threads, 4-row strips)

// ===== generic BN-final: reduce per-block partials -> scale/shift =====
__global__ __launch_bounds__(256) void k_bnfinal(const float* __restrict__ psum,
    const float* __restrict__ psq, const float* __restrict__ g, const float* __restrict__ bbias,
    float* __restrict__ sc, float* __restrict__ sh, int NB, float invN) {
  int c = blockIdx.x, tid = threadIdx.x;
  float s = 0.f, q = 0.f;
  for (int k = tid; k < NB; k += 256) { s += psum[c * NB + k]; q += psq[c * NB + k]; }
  __shared__ float ss[256], qq[256];
  ss[tid] = s; qq[tid] = q;
  __syncthreads();
  for (int st = 128; st > 0; st >>= 1) {
    if (tid < st) { ss[tid] += ss[tid + st]; qq[tid] += qq[tid + st]; }
    __syncthreads();
  }
  if (tid == 0) {
    float mean = ss[0] * invN;
    float var = fmaxf(qq[0] * invN - mean * mean, 0.f);
    float scale = g[c] / sqrtf(var + 1e-5f);
    sc[c] = scale; sh[c] = bbias[c] - mean * scale;
  }
}

// ===== weight prep: BuildCost shuffle + pointwise transposes, one dispatch =====
// wt: WT[((g*7+c)*81 + u*9+v)*16 + o]  (81648)
// wpt: [a0pw^T (144x180) | 4x ampw^T (180x180) | lpw^T (180x9)]  (157140)
__global__ __launch_bounds__(256) void k_wprep(const float* __restrict__ bcw,
    const float* __restrict__ a0pw, const float* __restrict__ ampw, const float* __restrict__ lpw,
    float* __restrict__ wt, float* __restrict__ wpt) {
  int k = blockIdx.x * 256 + threadIdx.x;
  if (k < 81648) {
    int o = k & 15; int rest = k >> 4;
    int r81 = rest % 81; int gc = rest / 81;
    int c = gc % 7, g = gc / 7;
    wt[k] = bcw[((g * 16 + o) * 7 + c) * 81 + r81];
    return;
  }
  int t = k - 81648;
  if (t < 25920) {                                   // a0pw [180][144] -> [c][o]
    int c = t / 180, o = t % 180;
    wpt[t] = a0pw[o * 144 + c];
  } else if (t < 25920 + 129600) {                   // ampw [m][180][180] -> [m][c][o]
    int t2 = t - 25920;
    int m = t2 / 32400, r = t2 % 32400;
    int c = r / 180, o = r % 180;
    wpt[t] = ampw[m * 32400 + o * 180 + c];
  } else if (t < 25920 + 129600 + 1620) {            // lpw [9][180] -> [c][o]
    int t2 = t - 25920 - 129600;
    int c = t2 / 9, o = t2 % 9;
    wpt[t] = lpw[o * 180 + c];
  }
}

// ===== feature conv0: 1->7 from raw x, branchless clamped window, fused stats =====
__global__ __launch_bounds__(256) void k_featconv0(const float* __restrict__ x,
    const float* __restrict__ w, float* __restrict__ out,
    float* __restrict__ psum, float* __restrict__ psq) {
  int blk = blockIdx.x, tid = threadIdx.x;
  int view = blk / 9, q = blk % 9;
  int b = view / 81, uv = view % 81;
  int u = uv / 9, v = uv % 9;
  int widx = q * 256 + tid;
  int j = widx % HH, i0 = (widx / HH) * 4;
  const float* bx = x + (size_t)b * PLANE_F + (u * HH) * 864 + v * HH;
  int off[6][3]; float m[6][3];
  #pragma unroll
  for (int r6 = 0; r6 < 6; r6++) {
    int ii = i0 + r6 - 1;
    float mi = ((unsigned)ii < 96u) ? 1.f : 0.f;
    int iic = min(max(ii, 0), 95);
    #pragma unroll
    for (int dx = 0; dx < 3; dx++) {
      int jj = j + dx - 1;
      float mj = ((unsigned)jj < 96u) ? 1.f : 0.f;
      int jjc = min(max(jj, 0), 95);
      off[r6][dx] = iic * 864 + jjc;
      m[r6][dx] = mi * mj;
    }
  }
  float win[6][3];
  #pragma unroll
  for (int r6 = 0; r6 < 6; r6++)
    #pragma unroll
    for (int dx = 0; dx < 3; dx++)
      win[r6][dx] = bx[off[r6][dx]] * m[r6][dx];
  float acc[4][7];
  #pragma unroll
  for (int px = 0; px < 4; px++)
    #pragma unroll
    for (int o = 0; o < 7; o++) acc[px][o] = 0.f;
  #pragma unroll
  for (int o = 0; o < 7; o++) {
    const float* wc = w + o * 9;
    #pragma unroll
    for (int ky = 0; ky < 3; ky++)
      #pragma unroll
      for (int kx = 0; kx < 3; kx++) {
        float wv = wc[ky * 3 + kx];
        #pragma unroll
        for (int px = 0; px < 4; px++)
          acc[px][o] = fmaf(win[px + ky][kx], wv, acc[px][o]);
      }
  }
  #pragma unroll
  for (int o = 0; o < 7; o++) {
    float* op = out + ((size_t)(b * 7 + o)) * PLANE_F + uv * PLANE_A + i0 * HH + j;
    #pragma unroll
    for (int px = 0; px < 4; px++) op[px * HH] = acc[px][o];
  }
  float sv[7], qv[7];
  #pragma unroll
  for (int o = 0; o < 7; o++) {
    sv[o] = acc[0][o] + acc[1][o] + acc[2][o] + acc[3][o];
    qv[o] = acc[0][o]*acc[0][o] + acc[1][o]*acc[1][o] + acc[2][o]*acc[2][o] + acc[3][o]*acc[3][o];
  }
  #pragma unroll
  for (int off2 = 32; off2 > 0; off2 >>= 1)
    #pragma unroll
    for (int o = 0; o < 7; o++) { sv[o] += __shfl_down(sv[o], off2); qv[o] += __shfl_down(qv[o], off2); }
  __shared__ float red[4][14];
  int wave = tid >> 6, lane = tid & 63;
  if (lane == 0) {
    #pragma unroll
    for (int o = 0; o < 7; o++) { red[wave][o] = sv[o]; red[wave][7 + o] = qv[o]; }
  }
  __syncthreads();
  if (tid < 14) {
    float t4 = red[0][tid] + red[1][tid] + red[2][tid] + red[3][tid];
    if (tid < 7) psum[tid * NBLK_FEAT + blk] = t4;
    else         psq[(tid - 7) * NBLK_FEAT + blk] = t4;
  }
}

// ===== feature conv: 7->7, branchless clamped window, fused BN+ReLU + stats =====
__global__ __launch_bounds__(256) void k_featconv4(const float* __restrict__ in,
    const float* __restrict__ w, const float* __restrict__ sc, const float* __restrict__ sh,
    float* __restrict__ out, float* __restrict__ psum, float* __restrict__ psq) {
  int blk = blockIdx.x, tid = threadIdx.x;
  int view = blk / 9, q = blk % 9;
  int b = view / 81, uv = view % 81;
  int widx = q * 256 + tid;
  int j = widx % HH, i0 = (widx / HH) * 4;
  int off[6][3]; float m[6][3];
  #pragma unroll
  for (int r6 = 0; r6 < 6; r6++) {
    int ii = i0 + r6 - 1;
    float mi = ((unsigned)ii < 96u) ? 1.f : 0.f;
    int iic = min(max(ii, 0), 95);
    #pragma unroll
    for (int dx = 0; dx < 3; dx++) {
      int jj = j + dx - 1;
      float mj = ((unsigned)jj < 96u) ? 1.f : 0.f;
      int jjc = min(max(jj, 0), 95);
      off[r6][dx] = iic * HH + jjc;
      m[r6][dx] = mi * mj;
    }
  }
  float acc[4][7];
  #pragma unroll
  for (int px = 0; px < 4; px++)
    #pragma unroll
    for (int o = 0; o < 7; o++) acc[px][o] = 0.f;
  #pragma unroll 1
  for (int c = 0; c < 7; c++) {
    const float* ip = in + ((size_t)(b * 7 + c)) * PLANE_F + uv * PLANE_A;
    float s = sc[c], h2 = sh[c];
    float win[6][3];
    #pragma unroll
    for (int r6 = 0; r6 < 6; r6++)
      #pragma unroll
      for (int dx = 0; dx < 3; dx++) {
        float vv = ip[off[r6][dx]];
        win[r6][dx] = fmaxf(fmaf(vv, s, h2), 0.f) * m[r6][dx];
      }
    #pragma unroll
    for (int o = 0; o < 7; o++) {
      const float* wc = w + (o * 7 + c) * 9;
      #pragma unroll
      for (int ky = 0; ky < 3; ky++)
        #pragma unroll
        for (int kx = 0; kx < 3; kx++) {
          float wv = wc[ky * 3 + kx];
          #pragma unroll
          for (int px = 0; px < 4; px++)
            acc[px][o] = fmaf(win[px + ky][kx], wv, acc[px][o]);
        }
    }
  }
  #pragma unroll
  for (int o = 0; o < 7; o++) {
    float* op = out + ((size_t)(b * 7 + o)) * PLANE_F + uv * PLANE_A + i0 * HH + j;
    #pragma unroll
    for (int px = 0; px < 4; px++) op[px * HH] = acc[px][o];
  }
  float sv[7], qv[7];
  #pragma unroll
  for (int o = 0; o < 7; o++) {
    sv[o] = acc[0][o] + acc[1][o] + acc[2][o] + acc[3][o];
    qv[o] = acc[0][o]*acc[0][o] + acc[1][o]*acc[1][o] + acc[2][o]*acc[2][o] + acc[3][o]*acc[3][o];
  }
  #pragma unroll
  for (int off2 = 32; off2 > 0; off2 >>= 1)
    #pragma unroll
    for (int o = 0; o < 7; o++) { sv[o] += __shfl_down(sv[o], off2); qv[o] += __shfl_down(qv[o], off2); }
  __shared__ float red[4][14];
  int wave = tid >> 6, lane = tid & 63;
  if (lane == 0) {
    #pragma unroll
    for (int o = 0; o < 7; o++) { red[wave][o] = sv[o]; red[wave][7 + o] = qv[o]; }
  }
  __syncthreads();
  if (tid < 14) {
    float t4 = red[0][tid] + red[1][tid] + red[2][tid] + red[3][tid];
    if (tid < 7) psum[tid * NBLK_FEAT + blk] = t4;
    else         psq[(tid - 7) * NBLK_FEAT + blk] = t4;
  }
}

// ===== BuildCost: SGPR weights, hoisted offsets/masks, distance-2 prefetch =====
// grid (18, 36, 2): x = gg (g*2+half, fastest for L3 reuse), y = pos block, z = b
__global__ __launch_bounds__(256) void k_buildcost(const float* __restrict__ F,
    const float* __restrict__ sc, const float* __restrict__ sh,
    const float* __restrict__ wt, float* __restrict__ cv) {
  int gg = blockIdx.x, b = blockIdx.z, tid = threadIdx.x;
  int g = gg >> 1, half = gg & 1;
  int d = g - 4;
  bool flip = d > 0;
  int p = blockIdx.y * 256 + tid;
  int i = p / HH, j = p % HH;
  int ubase[9]; float mi[9]; int voff[9]; float mj[9];
  #pragma unroll
  for (int u = 0; u < 9; u++) {
    int ii = i + d * (4 - u);
    mi[u] = ((unsigned)ii < 96u) ? 1.f : 0.f;
    ubase[u] = u * 9 * PLANE_A + min(max(ii, 0), 95) * HH;
  }
  #pragma unroll
  for (int v = 0; v < 9; v++) {
    int jj = j + d * (4 - v);
    mj[v] = ((unsigned)jj < 96u) ? 1.f : 0.f;
    voff[v] = v * PLANE_A + min(max(jj, 0), 95);
  }
  float acc[8];
  #pragma unroll
  for (int o = 0; o < 8; o++) acc[o] = 0.f;
  const float* Fb = F + ((size_t)b * 7) * PLANE_F;
  auto LD = [&](int cu, float* dst) {
    int c = cu / 9, u = cu - c * 9;
    const float* base = Fb + (size_t)c * PLANE_F + ubase[u];
    #pragma unroll
    for (int v = 0; v < 9; v++) dst[v] = base[voff[v]];
  };
  float buf[2][9];
  LD(0, buf[0]);
  LD(1, buf[1]);
  #pragma unroll 1
  for (int cu = 0; cu < 63; cu++) {
    int c = cu / 9, u = cu - c * 9;
    int pb = cu & 1;
    float cr[9];
    #pragma unroll
    for (int v = 0; v < 9; v++) cr[v] = buf[pb][v];
    int nf = cu + 2;
    if (nf < 63) LD(nf, buf[pb]);
    float s = sc[c], h2 = sh[c];                    // uniform -> s_load
    float mrow = mi[u];
    int uw = flip ? 8 - u : u;
    const float* wb = wt + ((size_t)((g * 7 + c) * 81 + uw * 9)) * 16 + half * 8;
    #pragma unroll
    for (int v = 0; v < 9; v++) {
      float a = fmaxf(fmaf(cr[v], s, h2), 0.f) * (mrow * mj[v]);
      int vw = flip ? 8 - v : v;
      const float* wp = wb + vw * 16;               // uniform -> s_load
      #pragma unroll
      for (int o = 0; o < 8; o++) acc[o] = fmaf(wp[o], a, acc[o]);
    }
  }
  size_t cvb = ((size_t)(b * 144 + g * 16 + half * 8)) * PLANE_A + p;
  #pragma unroll
  for (int o = 0; o < 8; o++) cv[cvb + o * PLANE_A] = acc[o];
}

// ===== depthwise 3x3 pad=1, fused input BN+ReLU + fused output stats =====
template<bool AFF>
__global__ __launch_bounds__(256) void k_dwconv(const float* __restrict__ in,
    const float* __restrict__ w, const float* __restrict__ isc, const float* __restrict__ ish,
    float* __restrict__ out, float* __restrict__ psum, float* __restrict__ psq, int C) {
  int blk = blockIdx.x, tid = threadIdx.x;
  int t = blk * 256 + tid;
  int j = t % HH; int r = t / HH; int i = r % HH; r /= HH; int c = r % C; int b = r / C;
  float s  = AFF ? isc[c] : 1.f;
  float h2 = AFF ? ish[c] : 0.f;
  const float* ip = in + ((size_t)(b * C + c)) * PLANE_A;
  float acc = 0.f;
  #pragma unroll
  for (int ky = 0; ky < 3; ky++) {
    int ii = i + ky - 1;
    if ((unsigned)ii >= (unsigned)HH) continue;
    #pragma unroll
    for (int kx = 0; kx < 3; kx++) {
      int jj = j + kx - 1;
      if ((unsigned)jj >= (unsigned)HH) continue;
      float v = ip[ii * HH + jj];
      if (AFF) v = fmaxf(fmaf(v, s, h2), 0.f);
      acc = fmaf(w[c * 9 + ky * 3 + kx], v, acc);
    }
  }
  out[t] = acc;
  float sv = acc, qv = acc * acc;
  #pragma unroll
  for (int off = 32; off > 0; off >>= 1) { sv += __shfl_down(sv, off); qv += __shfl_down(qv, off); }
  __shared__ float red[4][2];
  int wave = tid >> 6, lane = tid & 63;
  if (lane == 0) { red[wave][0] = sv; red[wave][1] = qv; }
  __syncthreads();
  if (tid == 0) {
    float S = red[0][0] + red[1][0] + red[2][0] + red[3][0];
    float Q = red[0][1] + red[1][1] + red[2][1] + red[3][1];
    int chunk = blk % 36; int rr = blk / 36; int c2 = rr % C; int b2 = rr / C;
    psum[c2 * 72 + b2 * 36 + chunk] = S;
    psq [c2 * 72 + b2 * 36 + chunk] = Q;
  }
}

// ===== pointwise conv: transposed weights (contiguous s_loadx4), 12 out/thread =====
// grid (15, 72): x = output group (12 outputs), y = position block
// wpt layout: [c][o], row length 180
template<int K>
__global__ __launch_bounds__(256) void k_pwconv(const float* __restrict__ in,
    const float* __restrict__ sc, const float* __restrict__ sh,
    const float* __restrict__ wpt, float* __restrict__ out,
    float* __restrict__ psum, float* __restrict__ psq) {
  int tid = threadIdx.x;
  int posblk = blockIdx.y;
  int p = posblk * 256 + tid;
  int b = p / PLANE_A, pp = p - b * PLANE_A;
  int obase = blockIdx.x * 12;
  float acc[12];
  #pragma unroll
  for (int o = 0; o < 12; o++) acc[o] = 0.f;
  const float* ib = in + (size_t)b * K * PLANE_A + pp;
  float xn[4];
  #pragma unroll
  for (int q2 = 0; q2 < 4; q2++) xn[q2] = ib[(size_t)q2 * PLANE_A];
  #pragma unroll 1
  for (int c0 = 0; c0 < K; c0 += 4) {
    float xv[4];
    #pragma unroll
    for (int q2 = 0; q2 < 4; q2++) xv[q2] = xn[q2];
    if (c0 + 4 < K) {
      #pragma unroll
      for (int q2 = 0; q2 < 4; q2++) xn[q2] = ib[(size_t)(c0 + 4 + q2) * PLANE_A];
    }
    #pragma unroll
    for (int q2 = 0; q2 < 4; q2++) {
      int c = c0 + q2;
      float v = fmaxf(fmaf(xv[q2], sc[c], sh[c]), 0.f);
      const float* wc = wpt + (size_t)c * 180 + obase;  // uniform, contiguous x12
      #pragma unroll
      for (int o = 0; o < 12; o++)
        acc[o] = fmaf(wc[o], v, acc[o]);
    }
  }
  #pragma unroll
  for (int o = 0; o < 12; o++)
    out[((size_t)(b * 180 + obase + o)) * PLANE_A + pp] = acc[o];
  __shared__ float rs[4][12], rq[4][12];
  int wave = tid >> 6, lane = tid & 63;
  #pragma unroll
  for (int o = 0; o < 12; o++) {
    float s = acc[o], q = acc[o] * acc[o];
    #pragma unroll
    for (int off = 32; off > 0; off >>= 1) { s += __shfl_down(s, off); q += __shfl_down(q, off); }
    if (lane == 0) { rs[wave][o] = s; rq[wave][o] = q; }
  }
  __syncthreads();
  if (tid < 12)
    psum[(obase + tid) * 72 + posblk] = rs[0][tid] + rs[1][tid] + rs[2][tid] + rs[3][tid];
  else if (tid < 24) {
    int o = tid - 12;
    psq[(obase + o) * 72 + posblk] = rq[0][o] + rq[1][o] + rq[2][o] + rq[3][o];
  }
}

// ===== final: 1x1 conv 180->9 (transposed wt) + softmax + expectation =====
__global__ __launch_bounds__(256) void k_final(const float* __restrict__ in,
    const float* __restrict__ sc, const float* __restrict__ sh,
    const float* __restrict__ wpt, float* __restrict__ out) {
  int tid = threadIdx.x;
  int t = blockIdx.x * 256 + tid;
  int b = t / PLANE_A, p = t - b * PLANE_A;
  const float* ib = in + (size_t)b * 180 * PLANE_A + p;
  float acc[9];
  #pragma unroll
  for (int o = 0; o < 9; o++) acc[o] = 0.f;
  float xn[4];
  #pragma unroll
  for (int q2 = 0; q2 < 4; q2++) xn[q2] = ib[(size_t)q2 * PLANE_A];
  #pragma unroll 1
  for (int c0 = 0; c0 < 180; c0 += 4) {
    float xv[4];
    #pragma unroll
    for (int q2 = 0; q2 < 4; q2++) xv[q2] = xn[q2];
    if (c0 + 4 < 180) {
      #pragma unroll
      for (int q2 = 0; q2 < 4; q2++) xn[q2] = ib[(size_t)(c0 + 4 + q2) * PLANE_A];
    }
    #pragma unroll
    for (int q2 = 0; q2 < 4; q2++) {
      int c = c0 + q2;
      float v = fmaxf(fmaf(xv[q2], sc[c], sh[c]), 0.f);
      const float* wc = wpt + (size_t)c * 9;        // uniform, contiguous x9
      #pragma unroll
      for (int o = 0; o < 9; o++) acc[o] = fmaf(wc[o], v, acc[o]);
    }
  }
  float m = acc[0];
  #pragma unroll
  for (int o = 1; o < 9; o++) m = fmaxf(m, acc[o]);
  float se = 0.f, num = 0.f;
  #pragma unroll
  for (int o = 0; o < 9; o++) {
    float e = expf(acc[o] - m);
    se += e;
    num += (float)(o - 4) * e;
  }
  out[t] = num / se;
}

extern "C" void kernel_launch(void* const* d_in, const int* in_sizes, int n_in,
                              void* d_out, int out_size, void* d_ws, size_t ws_size,
                              hipStream_t stream) {
  const float* x    = (const float*)d_in[0];
  const float* fw0  = (const float*)d_in[1];
  const float* fg0  = (const float*)d_in[2];
  const float* fb0  = (const float*)d_in[3];
  const float* fw   = (const float*)d_in[4];
  const float* fg   = (const float*)d_in[5];
  const float* fb   = (const float*)d_in[6];
  const float* bcw  = (const float*)d_in[7];
  const float* a0dw = (const float*)d_in[8];
  const float* a0dg = (const float*)d_in[9];
  const float* a0db = (const float*)d_in[10];
  const float* a0pw = (const float*)d_in[11];
  const float* a0pg = (const float*)d_in[12];
  const float* a0pb = (const float*)d_in[13];
  const float* amdw = (const float*)d_in[14];
  const float* amdg = (const float*)d_in[15];
  const float* amdb = (const float*)d_in[16];
  const float* ampw = (const float*)d_in[17];
  const float* ampg = (const float*)d_in[18];
  const float* ampb = (const float*)d_in[19];
  const float* ldw  = (const float*)d_in[20];
  const float* ldg  = (const float*)d_in[21];
  const float* ldb  = (const float*)d_in[22];
  const float* lpw  = (const float*)d_in[23];
  float* outp = (float*)d_out;

  float* FA    = (float*)d_ws;
  float* FB    = FA + (size_t)BB * 7 * PLANE_F;
  float* CV    = FB + (size_t)BB * 7 * PLANE_F;
  float* GA    = CV + (size_t)BB * 144 * PLANE_A;
  float* GB    = GA + (size_t)BB * 180 * PLANE_A;
  float* PSUM  = GB + (size_t)BB * 180 * PLANE_A;   // 7*1458 / 180*72 both fit
  float* PSQ   = PSUM + 180 * 288;
  float* SC    = PSQ + 180 * 288;
  float* SH    = SC + 180;
  float* WT    = SH + 180;                           // 81648
  float* WPT   = WT + 81648;                         // 157140
  float* WPT_A0 = WPT;                               // [144][180]
  float* WPT_AM = WPT + 25920;                       // 4 x [180][180]
  float* WPT_L  = WPT + 25920 + 129600;              // [180][9]

  const float invNbig = 1.0f / (float)(BB * PLANE_F);
  const float invNsmall = 1.0f / (float)(BB * PLANE_A);

  // weight prep (BuildCost shuffle + pointwise transposes), one dispatch
  k_wprep<<<(238788 + 255) / 256, 256, 0, stream>>>(bcw, a0pw, ampw, lpw, WT, WPT);

  // feature extraction (SAI layout), stats fused into conv blocks
  k_featconv0<<<NBLK_FEAT, 256, 0, stream>>>(x, fw0, FA, PSUM, PSQ);
  k_bnfinal<<<7, 256, 0, stream>>>(PSUM, PSQ, fg0, fb0, SC, SH, NBLK_FEAT, invNbig);

  float* cur = FA; float* nxt = FB;
  for (int i = 0; i < 6; i++) {
    k_featconv4<<<NBLK_FEAT, 256, 0, stream>>>(cur, fw + i * 441, SC, SH, nxt, PSUM, PSQ);
    k_bnfinal<<<7, 256, 0, stream>>>(PSUM, PSQ, fg + i * 7, fb + i * 7, SC, SH, NBLK_FEAT, invNbig);
    float* tmp = cur; cur = nxt; nxt = tmp;
  }

  // BuildCost (SGPR weights, hoisted masks, distance-2 prefetch)
  k_buildcost<<<dim3(18, 36, 2), 256, 0, stream>>>(cur, SC, SH, WT, CV);

  // aggregation (stats fused into producers; transposed pw weights)
  k_dwconv<false><<<BB * 144 * 36, 256, 0, stream>>>(CV, a0dw, nullptr, nullptr, GA, PSUM, PSQ, 144);
  k_bnfinal<<<144, 256, 0, stream>>>(PSUM, PSQ, a0dg, a0db, SC, SH, 72, invNsmall);
  k_pwconv<144><<<dim3(15, 72), 256, 0, stream>>>(GA, SC, SH, WPT_A0, GB, PSUM, PSQ);
  k_bnfinal<<<180, 256, 0, stream>>>(PSUM, PSQ, a0pg, a0pb, SC, SH, 72, invNsmall);

  for (int m = 0; m < 4; m++) {
    k_dwconv<true><<<BB * 180 * 36, 256, 0, stream>>>(GB, amdw + m * 1620, SC, SH, GA, PSUM, PSQ, 180);
    k_bnfinal<<<180, 256, 0, stream>>>(PSUM, PSQ, amdg + m * 180, amdb + m * 180, SC, SH, 72, invNsmall);
    k_pwconv<180><<<dim3(15, 72), 256, 0, stream>>>(GA, SC, SH, WPT_AM + m * 32400, GB, PSUM, PSQ);
    k_bnfinal<<<180, 256, 0, stream>>>(PSUM, PSQ, ampg + m * 180, ampb + m * 180, SC, SH, 72, invNsmall);
  }

  k_dwconv<true><<<BB * 180 * 36, 256, 0, stream>>>(GB, ldw, SC, SH, GA, PSUM, PSQ, 180);
  k_bnfinal<<<180, 256, 0, stream>>>(PSUM, PSQ, ldg, ldb, SC, SH, 72, invNsmall);

  k_final<<<72, 256, 0, stream>>>(GA, SC, SH, WPT_L, outp);
}

// Round 9
// 821.761 us; speedup vs baseline: 1.3262x; 1.1700x over previous
//
#include <hip/hip_runtime.h>

#define ANG 9
#define HH 96
#define BB 2
#define PLANE_F (81*HH*HH)  // 746496 per channel (81 views x 96x96)
#define PLANE_A (HH*HH)     // 9216
#define NBLK_FEAT 1458      // BB*81*9 blocks (each: 256 threads, 4-row strips)

// ===== generic BN-final: reduce per-block partials -> scale/shift =====
__global__ __launch_bounds__(256) void k_bnfinal(const float* __restrict__ psum,
    const float* __restrict__ psq, const float* __restrict__ g, const float* __restrict__ bbias,
    float* __restrict__ sc, float* __restrict__ sh, int NB, float invN) {
  int c = blockIdx.x, tid = threadIdx.x;
  float s = 0.f, q = 0.f;
  for (int k = tid; k < NB; k += 256) { s += psum[c * NB + k]; q += psq[c * NB + k]; }
  __shared__ float ss[256], qq[256];
  ss[tid] = s; qq[tid] = q;
  __syncthreads();
  for (int st = 128; st > 0; st >>= 1) {
    if (tid < st) { ss[tid] += ss[tid + st]; qq[tid] += qq[tid + st]; }
    __syncthreads();
  }
  if (tid == 0) {
    float mean = ss[0] * invN;
    float var = fmaxf(qq[0] * invN - mean * mean, 0.f);
    float scale = g[c] / sqrtf(var + 1e-5f);
    sc[c] = scale; sh[c] = bbias[c] - mean * scale;
  }
}

// ===== weight prep: BuildCost shuffle + pointwise transposes, one dispatch =====
// wt: WT[((g*7+c)*81 + u*9+v)*16 + o]  (81648)
// wpt: [a0pw^T (144x180) | 4x ampw^T (180x180) | lpw^T (180x9)]  (157140)
__global__ __launch_bounds__(256) void k_wprep(const float* __restrict__ bcw,
    const float* __restrict__ a0pw, const float* __restrict__ ampw, const float* __restrict__ lpw,
    float* __restrict__ wt, float* __restrict__ wpt) {
  int k = blockIdx.x * 256 + threadIdx.x;
  if (k < 81648) {
    int o = k & 15; int rest = k >> 4;
    int r81 = rest % 81; int gc = rest / 81;
    int c = gc % 7, g = gc / 7;
    wt[k] = bcw[((g * 16 + o) * 7 + c) * 81 + r81];
    return;
  }
  int t = k - 81648;
  if (t < 25920) {                                   // a0pw [180][144] -> [c][o]
    int c = t / 180, o = t % 180;
    wpt[t] = a0pw[o * 144 + c];
  } else if (t < 25920 + 129600) {                   // ampw [m][180][180] -> [m][c][o]
    int t2 = t - 25920;
    int m = t2 / 32400, r = t2 % 32400;
    int c = r / 180, o = r % 180;
    wpt[t] = ampw[m * 32400 + o * 180 + c];
  } else if (t < 25920 + 129600 + 1620) {            // lpw [9][180] -> [c][o]
    int t2 = t - 25920 - 129600;
    int c = t2 / 9, o = t2 % 9;
    wpt[t] = lpw[o * 180 + c];
  }
}

// ===== feature conv0: 1->7 from raw x, branchless clamped window, fused stats =====
__global__ __launch_bounds__(256) void k_featconv0(const float* __restrict__ x,
    const float* __restrict__ w, float* __restrict__ out,
    float* __restrict__ psum, float* __restrict__ psq) {
  int blk = blockIdx.x, tid = threadIdx.x;
  int view = blk / 9, q = blk % 9;
  int b = view / 81, uv = view % 81;
  int u = uv / 9, v = uv % 9;
  int widx = q * 256 + tid;
  int j = widx % HH, i0 = (widx / HH) * 4;
  const float* bx = x + (size_t)b * PLANE_F + (u * HH) * 864 + v * HH;
  int off[6][3]; float m[6][3];
  #pragma unroll
  for (int r6 = 0; r6 < 6; r6++) {
    int ii = i0 + r6 - 1;
    float mi = ((unsigned)ii < 96u) ? 1.f : 0.f;
    int iic = min(max(ii, 0), 95);
    #pragma unroll
    for (int dx = 0; dx < 3; dx++) {
      int jj = j + dx - 1;
      float mj = ((unsigned)jj < 96u) ? 1.f : 0.f;
      int jjc = min(max(jj, 0), 95);
      off[r6][dx] = iic * 864 + jjc;
      m[r6][dx] = mi * mj;
    }
  }
  float win[6][3];
  #pragma unroll
  for (int r6 = 0; r6 < 6; r6++)
    #pragma unroll
    for (int dx = 0; dx < 3; dx++)
      win[r6][dx] = bx[off[r6][dx]] * m[r6][dx];
  float acc[4][7];
  #pragma unroll
  for (int px = 0; px < 4; px++)
    #pragma unroll
    for (int o = 0; o < 7; o++) acc[px][o] = 0.f;
  #pragma unroll
  for (int o = 0; o < 7; o++) {
    const float* wc = w + o * 9;
    #pragma unroll
    for (int ky = 0; ky < 3; ky++)
      #pragma unroll
      for (int kx = 0; kx < 3; kx++) {
        float wv = wc[ky * 3 + kx];
        #pragma unroll
        for (int px = 0; px < 4; px++)
          acc[px][o] = fmaf(win[px + ky][kx], wv, acc[px][o]);
      }
  }
  #pragma unroll
  for (int o = 0; o < 7; o++) {
    float* op = out + ((size_t)(b * 7 + o)) * PLANE_F + uv * PLANE_A + i0 * HH + j;
    #pragma unroll
    for (int px = 0; px < 4; px++) op[px * HH] = acc[px][o];
  }
  float sv[7], qv[7];
  #pragma unroll
  for (int o = 0; o < 7; o++) {
    sv[o] = acc[0][o] + acc[1][o] + acc[2][o] + acc[3][o];
    qv[o] = acc[0][o]*acc[0][o] + acc[1][o]*acc[1][o] + acc[2][o]*acc[2][o] + acc[3][o]*acc[3][o];
  }
  #pragma unroll
  for (int off2 = 32; off2 > 0; off2 >>= 1)
    #pragma unroll
    for (int o = 0; o < 7; o++) { sv[o] += __shfl_down(sv[o], off2); qv[o] += __shfl_down(qv[o], off2); }
  __shared__ float red[4][14];
  int wave = tid >> 6, lane = tid & 63;
  if (lane == 0) {
    #pragma unroll
    for (int o = 0; o < 7; o++) { red[wave][o] = sv[o]; red[wave][7 + o] = qv[o]; }
  }
  __syncthreads();
  if (tid < 14) {
    float t4 = red[0][tid] + red[1][tid] + red[2][tid] + red[3][tid];
    if (tid < 7) psum[tid * NBLK_FEAT + blk] = t4;
    else         psq[(tid - 7) * NBLK_FEAT + blk] = t4;
  }
}

// ===== feature conv: 7->7, branchless window + channel prefetch, fused stats =====
__global__ __launch_bounds__(256) void k_featconv4(const float* __restrict__ in,
    const float* __restrict__ w, const float* __restrict__ sc, const float* __restrict__ sh,
    float* __restrict__ out, float* __restrict__ psum, float* __restrict__ psq) {
  int blk = blockIdx.x, tid = threadIdx.x;
  int view = blk / 9, q = blk % 9;
  int b = view / 81, uv = view % 81;
  int widx = q * 256 + tid;
  int j = widx % HH, i0 = (widx / HH) * 4;
  int off[6][3]; float m[6][3];
  #pragma unroll
  for (int r6 = 0; r6 < 6; r6++) {
    int ii = i0 + r6 - 1;
    float mi = ((unsigned)ii < 96u) ? 1.f : 0.f;
    int iic = min(max(ii, 0), 95);
    #pragma unroll
    for (int dx = 0; dx < 3; dx++) {
      int jj = j + dx - 1;
      float mj = ((unsigned)jj < 96u) ? 1.f : 0.f;
      int jjc = min(max(jj, 0), 95);
      off[r6][dx] = iic * HH + jjc;
      m[r6][dx] = mi * mj;
    }
  }
  float acc[4][7];
  #pragma unroll
  for (int px = 0; px < 4; px++)
    #pragma unroll
    for (int o = 0; o < 7; o++) acc[px][o] = 0.f;
  const float* ipbase = in + ((size_t)(b * 7)) * PLANE_F + uv * PLANE_A;
  float pre[6][3];
  #pragma unroll
  for (int r6 = 0; r6 < 6; r6++)
    #pragma unroll
    for (int dx = 0; dx < 3; dx++)
      pre[r6][dx] = ipbase[off[r6][dx]];
  #pragma unroll 1
  for (int c = 0; c < 7; c++) {
    float s = sc[c], h2 = sh[c];
    float win[6][3];
    #pragma unroll
    for (int r6 = 0; r6 < 6; r6++)
      #pragma unroll
      for (int dx = 0; dx < 3; dx++)
        win[r6][dx] = fmaxf(fmaf(pre[r6][dx], s, h2), 0.f) * m[r6][dx];
    if (c < 6) {
      const float* ipn = ipbase + (size_t)(c + 1) * PLANE_F;
      #pragma unroll
      for (int r6 = 0; r6 < 6; r6++)
        #pragma unroll
        for (int dx = 0; dx < 3; dx++)
          pre[r6][dx] = ipn[off[r6][dx]];
    }
    #pragma unroll
    for (int o = 0; o < 7; o++) {
      const float* wc = w + (o * 7 + c) * 9;
      #pragma unroll
      for (int ky = 0; ky < 3; ky++)
        #pragma unroll
        for (int kx = 0; kx < 3; kx++) {
          float wv = wc[ky * 3 + kx];
          #pragma unroll
          for (int px = 0; px < 4; px++)
            acc[px][o] = fmaf(win[px + ky][kx], wv, acc[px][o]);
        }
    }
  }
  #pragma unroll
  for (int o = 0; o < 7; o++) {
    float* op = out + ((size_t)(b * 7 + o)) * PLANE_F + uv * PLANE_A + i0 * HH + j;
    #pragma unroll
    for (int px = 0; px < 4; px++) op[px * HH] = acc[px][o];
  }
  float sv[7], qv[7];
  #pragma unroll
  for (int o = 0; o < 7; o++) {
    sv[o] = acc[0][o] + acc[1][o] + acc[2][o] + acc[3][o];
    qv[o] = acc[0][o]*acc[0][o] + acc[1][o]*acc[1][o] + acc[2][o]*acc[2][o] + acc[3][o]*acc[3][o];
  }
  #pragma unroll
  for (int off2 = 32; off2 > 0; off2 >>= 1)
    #pragma unroll
    for (int o = 0; o < 7; o++) { sv[o] += __shfl_down(sv[o], off2); qv[o] += __shfl_down(qv[o], off2); }
  __shared__ float red[4][14];
  int wave = tid >> 6, lane = tid & 63;
  if (lane == 0) {
    #pragma unroll
    for (int o = 0; o < 7; o++) { red[wave][o] = sv[o]; red[wave][7 + o] = qv[o]; }
  }
  __syncthreads();
  if (tid < 14) {
    float t4 = red[0][tid] + red[1][tid] + red[2][tid] + red[3][tid];
    if (tid < 7) psum[tid * NBLK_FEAT + blk] = t4;
    else         psq[(tid - 7) * NBLK_FEAT + blk] = t4;
  }
}

// ===== BuildCost helper: branchless clamped 9-tap load (R6-proven, no dyn arrays) =====
__device__ __forceinline__ void bc_load(const float* __restrict__ F, int b, int c, int u,
    int d, int i, int j, float* raw, float* msk) {
  const float* Fc = F + ((size_t)(b * 7 + c)) * PLANE_F + (u * 9) * PLANE_A;
  int ii = i + d * (4 - u);
  float mi = ((unsigned)ii < 96u) ? 1.f : 0.f;
  int iic = min(max(ii, 0), 95);
  const float* Frow = Fc + iic * HH;
  #pragma unroll
  for (int v = 0; v < 9; v++) {
    int jj = j + d * (4 - v);
    float mj = ((unsigned)jj < 96u) ? 1.f : 0.f;
    int jjc = min(max(jj, 0), 95);
    raw[v] = Frow[v * PLANE_A + jjc];
    msk[v] = mi * mj;
  }
}

// ===== BuildCost: 8-o split, SGPR weights, prefetched branchless loads (R6) =====
// grid (18, 36, 2): x = gg (g*2+half, fastest for L3 reuse), y = pos block, z = b
__global__ __launch_bounds__(256) void k_buildcost(const float* __restrict__ F,
    const float* __restrict__ sc, const float* __restrict__ sh,
    const float* __restrict__ wt, float* __restrict__ cv) {
  int gg = blockIdx.x, b = blockIdx.z, tid = threadIdx.x;
  int g = gg >> 1, half = gg & 1;
  int d = g - 4;
  bool flip = d > 0;
  int p = blockIdx.y * 256 + tid;
  int i = p / HH, j = p % HH;
  float acc[8];
  #pragma unroll
  for (int o = 0; o < 8; o++) acc[o] = 0.f;
  float raw[9], msk[9];
  bc_load(F, b, 0, 0, d, i, j, raw, msk);
  #pragma unroll 1
  for (int cu = 0; cu < 63; cu++) {
    int c = cu / 9, u = cu - c * 9;
    float cr[9], cm[9];
    #pragma unroll
    for (int v = 0; v < 9; v++) { cr[v] = raw[v]; cm[v] = msk[v]; }
    if (cu + 1 < 63) {
      int cn = (cu + 1) / 9, un = (cu + 1) - cn * 9;
      bc_load(F, b, cn, un, d, i, j, raw, msk);
    }
    float s = sc[c], h2 = sh[c];
    int uw = flip ? 8 - u : u;
    const float* wbase = wt + ((size_t)((g * 7 + c) * 81 + uw * 9)) * 16 + half * 8;
    #pragma unroll
    for (int v = 0; v < 9; v++) {
      float a = fmaxf(fmaf(cr[v], s, h2), 0.f) * cm[v];
      int vw = flip ? 8 - v : v;
      const float* wp = wbase + vw * 16;            // uniform -> s_load
      #pragma unroll
      for (int o = 0; o < 8; o++) acc[o] = fmaf(wp[o], a, acc[o]);
    }
  }
  size_t cvb = ((size_t)(b * 144 + g * 16 + half * 8)) * PLANE_A + p;
  #pragma unroll
  for (int o = 0; o < 8; o++) cv[cvb + o * PLANE_A] = acc[o];
}

// ===== depthwise 3x3 pad=1, fused input BN+ReLU + fused output stats =====
template<bool AFF>
__global__ __launch_bounds__(256) void k_dwconv(const float* __restrict__ in,
    const float* __restrict__ w, const float* __restrict__ isc, const float* __restrict__ ish,
    float* __restrict__ out, float* __restrict__ psum, float* __restrict__ psq, int C) {
  int blk = blockIdx.x, tid = threadIdx.x;
  int t = blk * 256 + tid;
  int j = t % HH; int r = t / HH; int i = r % HH; r /= HH; int c = r % C; int b = r / C;
  float s  = AFF ? isc[c] : 1.f;
  float h2 = AFF ? ish[c] : 0.f;
  const float* ip = in + ((size_t)(b * C + c)) * PLANE_A;
  float acc = 0.f;
  #pragma unroll
  for (int ky = 0; ky < 3; ky++) {
    int ii = i + ky - 1;
    if ((unsigned)ii >= (unsigned)HH) continue;
    #pragma unroll
    for (int kx = 0; kx < 3; kx++) {
      int jj = j + kx - 1;
      if ((unsigned)jj >= (unsigned)HH) continue;
      float v = ip[ii * HH + jj];
      if (AFF) v = fmaxf(fmaf(v, s, h2), 0.f);
      acc = fmaf(w[c * 9 + ky * 3 + kx], v, acc);
    }
  }
  out[t] = acc;
  float sv = acc, qv = acc * acc;
  #pragma unroll
  for (int off = 32; off > 0; off >>= 1) { sv += __shfl_down(sv, off); qv += __shfl_down(qv, off); }
  __shared__ float red[4][2];
  int wave = tid >> 6, lane = tid & 63;
  if (lane == 0) { red[wave][0] = sv; red[wave][1] = qv; }
  __syncthreads();
  if (tid == 0) {
    float S = red[0][0] + red[1][0] + red[2][0] + red[3][0];
    float Q = red[0][1] + red[1][1] + red[2][1] + red[3][1];
    int chunk = blk % 36; int rr = blk / 36; int c2 = rr % C; int b2 = rr / C;
    psum[c2 * 72 + b2 * 36 + chunk] = S;
    psq [c2 * 72 + b2 * 36 + chunk] = Q;
  }
}

// ===== pointwise conv: transposed weights (contiguous s_loadx4), 12 out/thread =====
// grid (15, 72): x = output group (12 outputs), y = position block
// wpt layout: [c][o], row length 180
template<int K>
__global__ __launch_bounds__(256) void k_pwconv(const float* __restrict__ in,
    const float* __restrict__ sc, const float* __restrict__ sh,
    const float* __restrict__ wpt, float* __restrict__ out,
    float* __restrict__ psum, float* __restrict__ psq) {
  int tid = threadIdx.x;
  int posblk = blockIdx.y;
  int p = posblk * 256 + tid;
  int b = p / PLANE_A, pp = p - b * PLANE_A;
  int obase = blockIdx.x * 12;
  float acc[12];
  #pragma unroll
  for (int o = 0; o < 12; o++) acc[o] = 0.f;
  const float* ib = in + (size_t)b * K * PLANE_A + pp;
  float xn[4];
  #pragma unroll
  for (int q2 = 0; q2 < 4; q2++) xn[q2] = ib[(size_t)q2 * PLANE_A];
  #pragma unroll 1
  for (int c0 = 0; c0 < K; c0 += 4) {
    float xv[4];
    #pragma unroll
    for (int q2 = 0; q2 < 4; q2++) xv[q2] = xn[q2];
    if (c0 + 4 < K) {
      #pragma unroll
      for (int q2 = 0; q2 < 4; q2++) xn[q2] = ib[(size_t)(c0 + 4 + q2) * PLANE_A];
    }
    #pragma unroll
    for (int q2 = 0; q2 < 4; q2++) {
      int c = c0 + q2;
      float v = fmaxf(fmaf(xv[q2], sc[c], sh[c]), 0.f);
      const float* wc = wpt + (size_t)c * 180 + obase;  // uniform, contiguous x12
      #pragma unroll
      for (int o = 0; o < 12; o++)
        acc[o] = fmaf(wc[o], v, acc[o]);
    }
  }
  #pragma unroll
  for (int o = 0; o < 12; o++)
    out[((size_t)(b * 180 + obase + o)) * PLANE_A + pp] = acc[o];
  __shared__ float rs[4][12], rq[4][12];
  int wave = tid >> 6, lane = tid & 63;
  #pragma unroll
  for (int o = 0; o < 12; o++) {
    float s = acc[o], q = acc[o] * acc[o];
    #pragma unroll
    for (int off = 32; off > 0; off >>= 1) { s += __shfl_down(s, off); q += __shfl_down(q, off); }
    if (lane == 0) { rs[wave][o] = s; rq[wave][o] = q; }
  }
  __syncthreads();
  if (tid < 12)
    psum[(obase + tid) * 72 + posblk] = rs[0][tid] + rs[1][tid] + rs[2][tid] + rs[3][tid];
  else if (tid < 24) {
    int o = tid - 12;
    psq[(obase + o) * 72 + posblk] = rq[0][o] + rq[1][o] + rq[2][o] + rq[3][o];
  }
}

// ===== final: 1x1 conv 180->9 (transposed wt) + softmax + expectation =====
__global__ __launch_bounds__(256) void k_final(const float* __restrict__ in,
    const float* __restrict__ sc, const float* __restrict__ sh,
    const float* __restrict__ wpt, float* __restrict__ out) {
  int tid = threadIdx.x;
  int t = blockIdx.x * 256 + tid;
  int b = t / PLANE_A, p = t - b * PLANE_A;
  const float* ib = in + (size_t)b * 180 * PLANE_A + p;
  float acc[9];
  #pragma unroll
  for (int o = 0; o < 9; o++) acc[o] = 0.f;
  float xn[4];
  #pragma unroll
  for (int q2 = 0; q2 < 4; q2++) xn[q2] = ib[(size_t)q2 * PLANE_A];
  #pragma unroll 1
  for (int c0 = 0; c0 < 180; c0 += 4) {
    float xv[4];
    #pragma unroll
    for (int q2 = 0; q2 < 4; q2++) xv[q2] = xn[q2];
    if (c0 + 4 < 180) {
      #pragma unroll
      for (int q2 = 0; q2 < 4; q2++) xn[q2] = ib[(size_t)(c0 + 4 + q2) * PLANE_A];
    }
    #pragma unroll
    for (int q2 = 0; q2 < 4; q2++) {
      int c = c0 + q2;
      float v = fmaxf(fmaf(xv[q2], sc[c], sh[c]), 0.f);
      const float* wc = wpt + (size_t)c * 9;        // uniform, contiguous x9
      #pragma unroll
      for (int o = 0; o < 9; o++) acc[o] = fmaf(wc[o], v, acc[o]);
    }
  }
  float m = acc[0];
  #pragma unroll
  for (int o = 1; o < 9; o++) m = fmaxf(m, acc[o]);
  float se = 0.f, num = 0.f;
  #pragma unroll
  for (int o = 0; o < 9; o++) {
    float e = expf(acc[o] - m);
    se += e;
    num += (float)(o - 4) * e;
  }
  out[t] = num / se;
}

extern "C" void kernel_launch(void* const* d_in, const int* in_sizes, int n_in,
                              void* d_out, int out_size, void* d_ws, size_t ws_size,
                              hipStream_t stream) {
  const float* x    = (const float*)d_in[0];
  const float* fw0  = (const float*)d_in[1];
  const float* fg0  = (const float*)d_in[2];
  const float* fb0  = (const float*)d_in[3];
  const float* fw   = (const float*)d_in[4];
  const float* fg   = (const float*)d_in[5];
  const float* fb   = (const float*)d_in[6];
  const float* bcw  = (const float*)d_in[7];
  const float* a0dw = (const float*)d_in[8];
  const float* a0dg = (const float*)d_in[9];
  const float* a0db = (const float*)d_in[10];
  const float* a0pw = (const float*)d_in[11];
  const float* a0pg = (const float*)d_in[12];
  const float* a0pb = (const float*)d_in[13];
  const float* amdw = (const float*)d_in[14];
  const float* amdg = (const float*)d_in[15];
  const float* amdb = (const float*)d_in[16];
  const float* ampw = (const float*)d_in[17];
  const float* ampg = (const float*)d_in[18];
  const float* ampb = (const float*)d_in[19];
  const float* ldw  = (const float*)d_in[20];
  const float* ldg  = (const float*)d_in[21];
  const float* ldb  = (const float*)d_in[22];
  const float* lpw  = (const float*)d_in[23];
  float* outp = (float*)d_out;

  float* FA    = (float*)d_ws;
  float* FB    = FA + (size_t)BB * 7 * PLANE_F;
  float* CV    = FB + (size_t)BB * 7 * PLANE_F;
  float* GA    = CV + (size_t)BB * 144 * PLANE_A;
  float* GB    = GA + (size_t)BB * 180 * PLANE_A;
  float* PSUM  = GB + (size_t)BB * 180 * PLANE_A;   // 7*1458 / 180*72 both fit
  float* PSQ   = PSUM + 180 * 288;
  float* SC    = PSQ + 180 * 288;
  float* SH    = SC + 180;
  float* WT    = SH + 180;                           // 81648
  float* WPT   = WT + 81648;                         // 157140
  float* WPT_A0 = WPT;                               // [144][180]
  float* WPT_AM = WPT + 25920;                       // 4 x [180][180]
  float* WPT_L  = WPT + 25920 + 129600;              // [180][9]

  const float invNbig = 1.0f / (float)(BB * PLANE_F);
  const float invNsmall = 1.0f / (float)(BB * PLANE_A);

  // weight prep (BuildCost shuffle + pointwise transposes), one dispatch
  k_wprep<<<(238788 + 255) / 256, 256, 0, stream>>>(bcw, a0pw, ampw, lpw, WT, WPT);

  // feature extraction (SAI layout), stats fused into conv blocks
  k_featconv0<<<NBLK_FEAT, 256, 0, stream>>>(x, fw0, FA, PSUM, PSQ);
  k_bnfinal<<<7, 256, 0, stream>>>(PSUM, PSQ, fg0, fb0, SC, SH, NBLK_FEAT, invNbig);

  float* cur = FA; float* nxt = FB;
  for (int i = 0; i < 6; i++) {
    k_featconv4<<<NBLK_FEAT, 256, 0, stream>>>(cur, fw + i * 441, SC, SH, nxt, PSUM, PSQ);
    k_bnfinal<<<7, 256, 0, stream>>>(PSUM, PSQ, fg + i * 7, fb + i * 7, SC, SH, NBLK_FEAT, invNbig);
    float* tmp = cur; cur = nxt; nxt = tmp;
  }

  // BuildCost (R6-proven structure: SGPR weights, branchless dist-1 prefetch)
  k_buildcost<<<dim3(18, 36, 2), 256, 0, stream>>>(cur, SC, SH, WT, CV);

  // aggregation (stats fused into producers; transposed pw weights)
  k_dwconv<false><<<BB * 144 * 36, 256, 0, stream>>>(CV, a0dw, nullptr, nullptr, GA, PSUM, PSQ, 144);
  k_bnfinal<<<144, 256, 0, stream>>>(PSUM, PSQ, a0dg, a0db, SC, SH, 72, invNsmall);
  k_pwconv<144><<<dim3(15, 72), 256, 0, stream>>>(GA, SC, SH, WPT_A0, GB, PSUM, PSQ);
  k_bnfinal<<<180, 256, 0, stream>>>(PSUM, PSQ, a0pg, a0pb, SC, SH, 72, invNsmall);

  for (int m = 0; m < 4; m++) {
    k_dwconv<true><<<BB * 180 * 36, 256, 0, stream>>>(GB, amdw + m * 1620, SC, SH, GA, PSUM, PSQ, 180);
    k_bnfinal<<<180, 256, 0, stream>>>(PSUM, PSQ, amdg + m * 180, amdb + m * 180, SC, SH, 72, invNsmall);
    k_pwconv<180><<<dim3(15, 72), 256, 0, stream>>>(GA, SC, SH, WPT_AM + m * 32400, GB, PSUM, PSQ);
    k_bnfinal<<<180, 256, 0, stream>>>(PSUM, PSQ, ampg + m * 180, ampb + m * 180, SC, SH, 72, invNsmall);
  }

  k_dwconv<true><<<BB * 180 * 36, 256, 0, stream>>>(GB, ldw, SC, SH, GA, PSUM, PSQ, 180);
  k_bnfinal<<<180, 256, 0, stream>>>(PSUM, PSQ, ldg, ldb, SC, SH, 72, invNsmall);

  k_final<<<72, 256, 0, stream>>>(GA, SC, SH, WPT_L, outp);
}